// Round 1
// 851.348 us; speedup vs baseline: 1.0151x; 1.0151x over previous
//
#include <hip/hip_runtime.h>
#include <hip/hip_bf16.h>
#include <stdint.h>

// LittleBitLinear: y = [(x*v2) @ sign(V)^T * (v1*u2)] @ sign(U)^T * u1  (x2 branches) + bias
// All inputs FLOAT32, output FLOAT32. Fold scales into binarized weights -> two bf16 GEMMs.
//   Xb  [8192][4096]  bf16 copy of x
//   Wb1 [2048][4096]  bf16 (B^T layout), rows 0..1023 branch1, 1024..2047 branch2
//   H   [8192][2048]  bf16 = Xb @ Wb1^T
//   Wb2 [4096][2048]  bf16 (B^T layout), K-concat of both branches, scaled by u1
//   Y   [8192][4096]  fp32 = H @ Wb2^T + bias
//
// Round 5: counters showed latency-bound (MfmaUtil 16.7, VALU 21, HBM 12%, occ 26).
//  (a) T3 minimum 2-phase: double-buffered LDS (2x16KB), prefetch tile k+1 via
//      global_load_lds BEFORE computing tile k; ONE barrier per K-step (was 2).
//      Staging latency now overlaps the ds_read+MFMA phase instead of being
//      fully exposed at a dedicated drain barrier.
//  (b) T1 XCD-aware bijective blockIdx swizzle (m204): contiguous grid chunk per
//      XCD -> A/B panel reuse hits the local L2 instead of L3 (FETCH_SIZE was
//      278MB vs 80MB working set -> loads were L3-class latency).
// NOTE: LDS dest pointer must be a real addrspace(3) cast of the shared-mem
// pointer (compiler addrspacecast). (uint32_t)(uintptr_t) truncation = garbage.

typedef __bf16 bf16x8 __attribute__((ext_vector_type(8)));
typedef float f32x4 __attribute__((ext_vector_type(4)));

__device__ __forceinline__ void async_copy16(const void* g, void* l) {
  __builtin_amdgcn_global_load_lds(
      (const __attribute__((address_space(1))) uint32_t*)g,
      (__attribute__((address_space(3))) uint32_t*)l,
      16, 0, 0);
}

__device__ __forceinline__ float sgn(float v) {
  return (v > 0.f) ? 1.f : ((v < 0.f) ? -1.f : 0.f);
}

__device__ __forceinline__ void store_out(float* p, float v) { *p = v; }
__device__ __forceinline__ void store_out(__hip_bfloat16* p, float v) { *p = __float2bfloat16(v); }

// fp32 -> bf16, 8 elements/thread, vectorized
__global__ __launch_bounds__(256) void convert_x(const float* __restrict__ x,
                                                 __hip_bfloat16* __restrict__ xb,
                                                 int n) {
  int i = (blockIdx.x * 256 + threadIdx.x) * 8;
  if (i >= n) return;
  const float4* p0 = (const float4*)(x + i);
  float4 a = p0[0], b = p0[1];
  __hip_bfloat16 o[8] = {
      __float2bfloat16(a.x), __float2bfloat16(a.y), __float2bfloat16(a.z), __float2bfloat16(a.w),
      __float2bfloat16(b.x), __float2bfloat16(b.y), __float2bfloat16(b.z), __float2bfloat16(b.w)};
  *(uint4*)(xb + i) = *(const uint4*)o;
}

// Wb1[s][k] = sign(V[s][k]) * v2[k] * v1[s] * u2[s]   (s<1024: branch1, else branch2)
__global__ __launch_bounds__(256) void prep_w1(
    const float* __restrict__ V, const float* __restrict__ v2,
    const float* __restrict__ v1, const float* __restrict__ u2,
    const float* __restrict__ V_R, const float* __restrict__ v2_R,
    const float* __restrict__ v1_R, const float* __restrict__ u2_R,
    __hip_bfloat16* __restrict__ W) {
  int g = blockIdx.x * 256 + threadIdx.x;  // one thread -> 8 consecutive k
  int k = (g & 511) * 8;                   // 4096 / 8 = 512 groups per row
  int s = g >> 9;                          // 0..2047
  const float *Vp, *v2p;
  float rs;
  if (s < 1024) {
    Vp = V + s * 4096 + k; v2p = v2 + k; rs = v1[s] * u2[s];
  } else {
    int ss = s - 1024;
    Vp = V_R + ss * 4096 + k; v2p = v2_R + k; rs = v1_R[ss] * u2_R[ss];
  }
  __hip_bfloat16 o[8];
#pragma unroll
  for (int e = 0; e < 8; ++e)
    o[e] = __float2bfloat16(sgn(Vp[e]) * v2p[e] * rs);
  *(uint4*)(W + s * 4096 + k) = *(const uint4*)o;
}

// Wb2[j][s] = sign(U[j][s]) * u1[j]  (s<1024 branch1, else branch2)
__global__ __launch_bounds__(256) void prep_w2(
    const float* __restrict__ U, const float* __restrict__ u1,
    const float* __restrict__ U_R, const float* __restrict__ u1_R,
    __hip_bfloat16* __restrict__ W) {
  int g = blockIdx.x * 256 + threadIdx.x;  // one thread -> 8 consecutive s
  int s = (g & 255) * 8;                   // 2048 / 8 = 256 groups per row
  int j = g >> 8;                          // 0..4095
  const float* Up;
  float sc;
  if (s < 1024) { Up = U + j * 1024 + s;            sc = u1[j]; }
  else          { Up = U_R + j * 1024 + (s - 1024); sc = u1_R[j]; }
  __hip_bfloat16 o[8];
#pragma unroll
  for (int e = 0; e < 8; ++e)
    o[e] = __float2bfloat16(sgn(Up[e]) * sc);
  *(uint4*)(W + j * 2048 + s) = *(const uint4*)o;
}

// C[M][N] = A[M][K] @ Bt[N][K]^T (+bias), bf16 in, fp32 acc.
// 128x128 block tile, 4 waves (2x2), each wave 64x64 = 4x4 MFMA 16x16x32 tiles.
// BK=32, double-buffered LDS (2 x 16KB). LDS chunk-major per buffer: slot s in
// [0,512): chunk=s>>7 (k-octet), row=s&127; cell=16B (8 bf16).
// global_load_lds dest = wave base + lane*16 (contiguous slots per wave).
//
// K-loop (2-phase):
//   prologue: stage(buf0, k=0); barrier (implies vmcnt(0))
//   iter:     stage(buf^1, k+32)   <- prefetch issued FIRST
//             ds_read + 16 MFMA from buf
//             barrier (drains vmcnt+lgkmcnt; prefetch had the compute phase in flight)
//   epilogue: compute last tile (no stage, no barrier)
template <typename OutT>
__global__ __launch_bounds__(256) void gemm_bt(
    const __hip_bfloat16* __restrict__ A,
    const __hip_bfloat16* __restrict__ Bt,
    OutT* __restrict__ C,
    const float* __restrict__ bias,
    int K, int N) {
  __shared__ char smem[32768];  // buf0: A [0,8K) B [8K,16K); buf1: +16K
  const int t = threadIdx.x;
  const int lane = t & 63;
  const int w = t >> 6;
  const int wm = (w >> 1) << 6;   // wave M offset in tile
  const int wn = (w & 1) << 6;    // wave N offset in tile

  // T1: XCD-aware bijective remap of linear workgroup id (m204 formula).
  // nwg is 1024 / 2048 here (divisible by 8 -> r==0), formula kept general.
  const int gx = gridDim.x;
  const int nwg = gx * gridDim.y;
  int lin = blockIdx.y * gx + blockIdx.x;
  {
    const int xcd = lin & 7, idx = lin >> 3;
    const int q = nwg >> 3, r = nwg & 7;
    const int base = (xcd < r) ? xcd * (q + 1) : r * (q + 1) + (xcd - r) * q;
    lin = base + idx;
  }
  const int bm = (lin / gx) << 7;
  const int bn = (lin % gx) << 7;

  const int quad = lane >> 4;
  const int l16 = lane & 15;

  f32x4 acc[4][4] = {};

  // staging: 512 slots per tile per operand, 256 threads -> 2 slots each
  const int s0 = t, s1 = t + 256;
  const int ch0 = s0 >> 7, r0 = s0 & 127;
  const int ch1 = s1 >> 7, r1 = s1 & 127;
  const __hip_bfloat16* gA0 = A + (bm + r0) * K + ch0 * 8;
  const __hip_bfloat16* gA1 = A + (bm + r1) * K + ch1 * 8;
  const __hip_bfloat16* gB0 = Bt + (bn + r0) * K + ch0 * 8;
  const __hip_bfloat16* gB1 = Bt + (bn + r1) * K + ch1 * 8;
  const int oA0 = s0 * 16, oA1 = s1 * 16;
  const int oB0 = 8192 + s0 * 16, oB1 = 8192 + s1 * 16;

  auto stage = [&](int buf, int k0) {
    char* base = smem + (buf << 14);
    async_copy16(gA0 + k0, base + oA0);
    async_copy16(gA1 + k0, base + oA1);
    async_copy16(gB0 + k0, base + oB0);
    async_copy16(gB1 + k0, base + oB1);
  };
  auto compute = [&](int buf) {
    const char* base = smem + (buf << 14);
    bf16x8 a[4], b[4];
#pragma unroll
    for (int i = 0; i < 4; ++i)
      a[i] = *(const bf16x8*)(base + ((quad << 7) + wm + (i << 4) + l16) * 16);
#pragma unroll
    for (int j = 0; j < 4; ++j)
      b[j] = *(const bf16x8*)(base + 8192 + ((quad << 7) + wn + (j << 4) + l16) * 16);
#pragma unroll
    for (int i = 0; i < 4; ++i)
#pragma unroll
      for (int j = 0; j < 4; ++j)
        acc[i][j] = __builtin_amdgcn_mfma_f32_16x16x32_bf16(a[i], b[j], acc[i][j], 0, 0, 0);
  };

  stage(0, 0);
  __syncthreads();  // vmcnt(0) drained at barrier: buf0 staged for all waves
  int cur = 0;
  for (int k0 = 32; k0 < K; k0 += 32) {
    stage(cur ^ 1, k0);   // prefetch next tile (flies during compute below)
    compute(cur);
    __syncthreads();      // drains prefetch + this iter's ds_reads; safe to flip
    cur ^= 1;
  }
  compute(cur);           // last tile: nothing to prefetch, no barrier needed

  // epilogue: C/D layout col=lane&15, row=quad*4+reg
#pragma unroll
  for (int j = 0; j < 4; ++j) {
    int col = bn + wn + (j << 4) + l16;
    float bv = bias ? bias[col] : 0.0f;
#pragma unroll
    for (int i = 0; i < 4; ++i) {
      int row0 = bm + wm + (i << 4) + (quad << 2);
#pragma unroll
      for (int r = 0; r < 4; ++r)
        store_out(&C[(row0 + r) * N + col], acc[i][j][r] + bv);
    }
  }
}

extern "C" void kernel_launch(void* const* d_in, const int* in_sizes, int n_in,
                              void* d_out, int out_size, void* d_ws, size_t ws_size,
                              hipStream_t stream) {
  const float* x    = (const float*)d_in[0];
  const float* V    = (const float*)d_in[1];
  const float* U    = (const float*)d_in[2];
  const float* v2   = (const float*)d_in[3];
  const float* v1   = (const float*)d_in[4];
  const float* u2   = (const float*)d_in[5];
  const float* u1   = (const float*)d_in[6];
  const float* V_R  = (const float*)d_in[7];
  const float* U_R  = (const float*)d_in[8];
  const float* v2_R = (const float*)d_in[9];
  const float* v1_R = (const float*)d_in[10];
  const float* u2_R = (const float*)d_in[11];
  const float* u1_R = (const float*)d_in[12];
  const float* bias = (const float*)d_in[13];

  __hip_bfloat16* Xb  = (__hip_bfloat16*)d_ws;          // 8192*4096
  __hip_bfloat16* Wb1 = Xb + 8192 * 4096;               // 2048*4096
  __hip_bfloat16* Wb2 = Wb1 + 2048 * 4096;              // 4096*2048
  __hip_bfloat16* H   = Wb2 + 4096 * 2048;              // 8192*2048
  float* Y = (float*)d_out;

  const int nx = 8192 * 4096;
  convert_x<<<nx / (256 * 8), 256, 0, stream>>>(x, Xb, nx);
  prep_w1<<<4096, 256, 0, stream>>>(V, v2, v1, u2, V_R, v2_R, v1_R, u2_R, Wb1);
  prep_w2<<<4096, 256, 0, stream>>>(U, u1, U_R, u1_R, Wb2);

  // H[8192][2048] = Xb @ Wb1^T
  gemm_bt<__hip_bfloat16><<<dim3(2048 / 128, 8192 / 128), 256, 0, stream>>>(
      Xb, Wb1, H, nullptr, 4096, 2048);
  // Y[8192][4096] = H @ Wb2^T + bias
  gemm_bt<float><<<dim3(4096 / 128, 8192 / 128), 256, 0, stream>>>(
      H, Wb2, Y, bias, 2048, 4096);
}

// Round 2
// 807.787 us; speedup vs baseline: 1.0699x; 1.0539x over previous
//
#include <hip/hip_runtime.h>
#include <hip/hip_bf16.h>
#include <stdint.h>

// LittleBitLinear: y = [(x*v2) @ sign(V)^T * (v1*u2)] @ sign(U)^T * u1  (x2 branches) + bias
// All inputs FLOAT32, output FLOAT32. Fold scales into binarized weights -> two bf16 GEMMs.
//   Xb  [8192][4096]  bf16 copy of x
//   Wb1 [2048][4096]  bf16 (B^T layout), rows 0..1023 branch1, 1024..2047 branch2
//   H   [8192][2048]  bf16 = Xb @ Wb1^T
//   Wb2 [4096][2048]  bf16 (B^T layout), K-concat of both branches, scaled by u1
//   Y   [8192][4096]  fp32 = H @ Wb2^T + bias
//
// Round 6: counters showed ~880 cy exposed load latency per K-step (MfmaUtil 18.5,
// FETCH 460MB vs 48MB minimum -> L2 thrash).
//  (a) T4 depth-2 pipeline: 3 LDS buffers (48KB), stages for tiles t+1,t+2 in
//      flight while computing tile t. Raw s_barrier + counted
//      "s_waitcnt vmcnt(4)" (NEVER vmcnt(0) in the main loop) -- __syncthreads
//      would drain vmcnt(0) and kill the pipeline. Last tile peeled with vmcnt(0).
//  (b) L2-aware swizzle: column-group-major block order (G=4 block-cols/group),
//      then contiguous-chunk-per-XCD. Each XCD keeps 4 B-panels (2-4MB) resident
//      in its private L2 and streams A-panels (each reused x4 by group cols).
//      Round-1's plain contiguous chunk made every XCD sweep the FULL B (16MB)
//      against 4MB L2 -> thrash (the 460MB FETCH).
// NOTE: LDS dest pointer must be a real addrspace(3) cast of the shared-mem
// pointer (compiler addrspacecast). (uint32_t)(uintptr_t) truncation = garbage.

typedef __bf16 bf16x8 __attribute__((ext_vector_type(8)));
typedef float f32x4 __attribute__((ext_vector_type(4)));

__device__ __forceinline__ void async_copy16(const void* g, void* l) {
  __builtin_amdgcn_global_load_lds(
      (const __attribute__((address_space(1))) uint32_t*)g,
      (__attribute__((address_space(3))) uint32_t*)l,
      16, 0, 0);
}

__device__ __forceinline__ float sgn(float v) {
  return (v > 0.f) ? 1.f : ((v < 0.f) ? -1.f : 0.f);
}

__device__ __forceinline__ void store_out(float* p, float v) { *p = v; }
__device__ __forceinline__ void store_out(__hip_bfloat16* p, float v) { *p = __float2bfloat16(v); }

// fp32 -> bf16, 8 elements/thread, vectorized
__global__ __launch_bounds__(256) void convert_x(const float* __restrict__ x,
                                                 __hip_bfloat16* __restrict__ xb,
                                                 int n) {
  int i = (blockIdx.x * 256 + threadIdx.x) * 8;
  if (i >= n) return;
  const float4* p0 = (const float4*)(x + i);
  float4 a = p0[0], b = p0[1];
  __hip_bfloat16 o[8] = {
      __float2bfloat16(a.x), __float2bfloat16(a.y), __float2bfloat16(a.z), __float2bfloat16(a.w),
      __float2bfloat16(b.x), __float2bfloat16(b.y), __float2bfloat16(b.z), __float2bfloat16(b.w)};
  *(uint4*)(xb + i) = *(const uint4*)o;
}

// Wb1[s][k] = sign(V[s][k]) * v2[k] * v1[s] * u2[s]   (s<1024: branch1, else branch2)
__global__ __launch_bounds__(256) void prep_w1(
    const float* __restrict__ V, const float* __restrict__ v2,
    const float* __restrict__ v1, const float* __restrict__ u2,
    const float* __restrict__ V_R, const float* __restrict__ v2_R,
    const float* __restrict__ v1_R, const float* __restrict__ u2_R,
    __hip_bfloat16* __restrict__ W) {
  int g = blockIdx.x * 256 + threadIdx.x;  // one thread -> 8 consecutive k
  int k = (g & 511) * 8;                   // 4096 / 8 = 512 groups per row
  int s = g >> 9;                          // 0..2047
  const float *Vp, *v2p;
  float rs;
  if (s < 1024) {
    Vp = V + s * 4096 + k; v2p = v2 + k; rs = v1[s] * u2[s];
  } else {
    int ss = s - 1024;
    Vp = V_R + ss * 4096 + k; v2p = v2_R + k; rs = v1_R[ss] * u2_R[ss];
  }
  __hip_bfloat16 o[8];
#pragma unroll
  for (int e = 0; e < 8; ++e)
    o[e] = __float2bfloat16(sgn(Vp[e]) * v2p[e] * rs);
  *(uint4*)(W + s * 4096 + k) = *(const uint4*)o;
}

// Wb2[j][s] = sign(U[j][s]) * u1[j]  (s<1024 branch1, else branch2)
__global__ __launch_bounds__(256) void prep_w2(
    const float* __restrict__ U, const float* __restrict__ u1,
    const float* __restrict__ U_R, const float* __restrict__ u1_R,
    __hip_bfloat16* __restrict__ W) {
  int g = blockIdx.x * 256 + threadIdx.x;  // one thread -> 8 consecutive s
  int s = (g & 255) * 8;                   // 2048 / 8 = 256 groups per row
  int j = g >> 8;                          // 0..4095
  const float* Up;
  float sc;
  if (s < 1024) { Up = U + j * 1024 + s;            sc = u1[j]; }
  else          { Up = U_R + j * 1024 + (s - 1024); sc = u1_R[j]; }
  __hip_bfloat16 o[8];
#pragma unroll
  for (int e = 0; e < 8; ++e)
    o[e] = __float2bfloat16(sgn(Up[e]) * sc);
  *(uint4*)(W + j * 2048 + s) = *(const uint4*)o;
}

// C[M][N] = A[M][K] @ Bt[N][K]^T (+bias), bf16 in, fp32 acc.
// 128x128 block tile, 4 waves (2x2), each wave 64x64 = 4x4 MFMA 16x16x32 tiles.
// BK=32. LDS: 3 buffers x 16KB (depth-2 prefetch pipeline). Per buffer,
// chunk-major: slot s in [0,512): chunk=s>>7 (k-octet), row=s&127; cell=16B.
// global_load_lds dest = wave base + lane*16 (wave-uniform-base constraint).
//
// K-loop (depth-2, counted vmcnt):
//   prologue: stage(0->buf0); stage(1->buf1)
//   iter t:   s_waitcnt vmcnt(4)  <- tile t landed (t+1's 4 loads may fly)
//             s_barrier            <- all threads' tile-t loads landed
//             stage(t+2 -> buf[(t+2)%3])   (overwrites buf of t-1; reads done)
//             compute(buf[t%3])    (stage loads fly across ~2 compute phases)
//   peeled last: vmcnt(0); barrier; compute.
template <typename OutT>
__global__ __launch_bounds__(256) void gemm_bt(
    const __hip_bfloat16* __restrict__ A,
    const __hip_bfloat16* __restrict__ Bt,
    OutT* __restrict__ C,
    const float* __restrict__ bias,
    int K, int N) {
  __shared__ char smem[49152];  // 3 x 16KB buffers; per buf: A [0,8K) B [8K,16K)
  const int t = threadIdx.x;
  const int lane = t & 63;
  const int w = t >> 6;
  const int wm = (w >> 1) << 6;   // wave M offset in tile
  const int wn = (w & 1) << 6;    // wave N offset in tile

  // L2-aware block swizzle:
  //  1) column-group-major order (G=4 block-cols per group): within a group,
  //     col varies fastest, then row -> consecutive ids share 4 B-panels.
  //  2) contiguous chunk per XCD (nwg % 8 == 0 for our grids) -> those
  //     consecutive ids co-reside on one XCD; its L2 holds the 4 B-panels.
  const int gx = gridDim.x;
  const int gy = gridDim.y;
  const int nwg = gx * gy;
  int lin = blockIdx.y * gx + blockIdx.x;
  {
    const int xcd = lin & 7, idx = lin >> 3, q = nwg >> 3;
    lin = xcd * q + idx;
  }
  const int grpsz = gy << 2;          // gy rows * 4 cols per group
  const int cg = lin / grpsz;
  const int rem = lin - cg * grpsz;
  const int bm = (rem >> 2) << 7;                  // row
  const int bn = ((cg << 2) + (rem & 3)) << 7;     // group*4 + col-in-group

  const int quad = lane >> 4;
  const int l16 = lane & 15;

  f32x4 acc[4][4] = {};

  // staging: 512 slots per tile per operand, 256 threads -> 2 slots each
  const int s0 = t, s1 = t + 256;
  const int ch0 = s0 >> 7, r0 = s0 & 127;
  const int ch1 = s1 >> 7, r1 = s1 & 127;
  const __hip_bfloat16* gA0 = A + (bm + r0) * K + ch0 * 8;
  const __hip_bfloat16* gA1 = A + (bm + r1) * K + ch1 * 8;
  const __hip_bfloat16* gB0 = Bt + (bn + r0) * K + ch0 * 8;
  const __hip_bfloat16* gB1 = Bt + (bn + r1) * K + ch1 * 8;
  const int oA0 = s0 * 16, oA1 = s1 * 16;
  const int oB0 = 8192 + s0 * 16, oB1 = 8192 + s1 * 16;

  auto stage = [&](int k0, int bufOff) {
    char* base = smem + bufOff;
    async_copy16(gA0 + k0, base + oA0);
    async_copy16(gA1 + k0, base + oA1);
    async_copy16(gB0 + k0, base + oB0);
    async_copy16(gB1 + k0, base + oB1);
  };
  auto compute = [&](int bufOff) {
    const char* base = smem + bufOff;
    bf16x8 a[4], b[4];
#pragma unroll
    for (int i = 0; i < 4; ++i)
      a[i] = *(const bf16x8*)(base + ((quad << 7) + wm + (i << 4) + l16) * 16);
#pragma unroll
    for (int j = 0; j < 4; ++j)
      b[j] = *(const bf16x8*)(base + 8192 + ((quad << 7) + wn + (j << 4) + l16) * 16);
#pragma unroll
    for (int i = 0; i < 4; ++i)
#pragma unroll
      for (int j = 0; j < 4; ++j)
        acc[i][j] = __builtin_amdgcn_mfma_f32_16x16x32_bf16(a[i], b[j], acc[i][j], 0, 0, 0);
  };

  const int NT = K >> 5;  // K/32 tiles (>= 64 here)
  stage(0, 0);
  stage(32, 16384);
  int cOff = 0;  // buffer offset of tile t ( (t%3)*16KB )
  for (int tt = 0; tt < NT - 1; ++tt) {
    // wait own tile-t stage (4 newest loads = tile t+1 may stay in flight)
    asm volatile("s_waitcnt vmcnt(4)" ::: "memory");
    __builtin_amdgcn_s_barrier();
    asm volatile("" ::: "memory");  // fence: no ds_read hoists above barrier
    if (tt + 2 < NT) {
      int sOff = cOff - 16384;      // (t+2)%3 slot == (t-1)%3 slot
      if (sOff < 0) sOff += 49152;
      stage((tt + 2) << 5, sOff);
    }
    compute(cOff);
    cOff += 16384;
    if (cOff == 49152) cOff = 0;
  }
  asm volatile("s_waitcnt vmcnt(0)" ::: "memory");
  __builtin_amdgcn_s_barrier();
  asm volatile("" ::: "memory");
  compute(cOff);

  // epilogue: C/D layout col=lane&15, row=quad*4+reg
#pragma unroll
  for (int j = 0; j < 4; ++j) {
    int col = bn + wn + (j << 4) + l16;
    float bv = bias ? bias[col] : 0.0f;
#pragma unroll
    for (int i = 0; i < 4; ++i) {
      int row0 = bm + wm + (i << 4) + (quad << 2);
#pragma unroll
      for (int r = 0; r < 4; ++r)
        store_out(&C[(row0 + r) * N + col], acc[i][j][r] + bv);
    }
  }
}

extern "C" void kernel_launch(void* const* d_in, const int* in_sizes, int n_in,
                              void* d_out, int out_size, void* d_ws, size_t ws_size,
                              hipStream_t stream) {
  const float* x    = (const float*)d_in[0];
  const float* V    = (const float*)d_in[1];
  const float* U    = (const float*)d_in[2];
  const float* v2   = (const float*)d_in[3];
  const float* v1   = (const float*)d_in[4];
  const float* u2   = (const float*)d_in[5];
  const float* u1   = (const float*)d_in[6];
  const float* V_R  = (const float*)d_in[7];
  const float* U_R  = (const float*)d_in[8];
  const float* v2_R = (const float*)d_in[9];
  const float* v1_R = (const float*)d_in[10];
  const float* u2_R = (const float*)d_in[11];
  const float* u1_R = (const float*)d_in[12];
  const float* bias = (const float*)d_in[13];

  __hip_bfloat16* Xb  = (__hip_bfloat16*)d_ws;          // 8192*4096
  __hip_bfloat16* Wb1 = Xb + 8192 * 4096;               // 2048*4096
  __hip_bfloat16* Wb2 = Wb1 + 2048 * 4096;              // 4096*2048
  __hip_bfloat16* H   = Wb2 + 4096 * 2048;              // 8192*2048
  float* Y = (float*)d_out;

  const int nx = 8192 * 4096;
  convert_x<<<nx / (256 * 8), 256, 0, stream>>>(x, Xb, nx);
  prep_w1<<<4096, 256, 0, stream>>>(V, v2, v1, u2, V_R, v2_R, v1_R, u2_R, Wb1);
  prep_w2<<<4096, 256, 0, stream>>>(U, u1, U_R, u1_R, Wb2);

  // H[8192][2048] = Xb @ Wb1^T
  gemm_bt<__hip_bfloat16><<<dim3(2048 / 128, 8192 / 128), 256, 0, stream>>>(
      Xb, Wb1, H, nullptr, 4096, 2048);
  // Y[8192][4096] = H @ Wb2^T + bias
  gemm_bt<float><<<dim3(4096 / 128, 8192 / 128), 256, 0, stream>>>(
      H, Wb2, Y, bias, 2048, 4096);
}

// Round 3
// 689.202 us; speedup vs baseline: 1.2539x; 1.1721x over previous
//
#include <hip/hip_runtime.h>
#include <hip/hip_bf16.h>
#include <stdint.h>

// LittleBitLinear: y = [(x*v2) @ sign(V)^T * (v1*u2)] @ sign(U)^T * u1  (x2 branches) + bias
// All inputs FLOAT32, output FLOAT32. Fold scales into binarized weights -> two bf16 GEMMs.
//   Xb  [8192][4096]  bf16 copy of x
//   Wb1 [2048][4096]  bf16 (B^T layout), rows 0..1023 branch1, 1024..2047 branch2
//   H   [8192][2048]  bf16 = Xb @ Wb1^T
//   Wb2 [4096][2048]  bf16 (B^T layout), K-concat of both branches, scaled by u1
//   Y   [8192][4096]  fp32 = H @ Wb2^T + bias
//
// Round 7: counters showed NOTHING saturated (Mfma 19.8, VALU 11, HBM 16%,
// LDS ~24 B/cy of ~100) -> serialization-bound: per K-step only 16 MFMA/wave
// between two block-wide barriers. Fix = m201 GEOMETRY with the proven loop:
//   - 256x256 block tile, 8 waves (2M x 4N), per-wave 128x64 output
//     -> 32 MFMA + 12 ds_read_b128 per wave per K-step (42.7 FLOP/LDS-byte)
//   - acc 8x4 f32x4 = 128 VGPRs; __launch_bounds__(512,2) -> <=256 VGPR, no spill
//   - LDS 2 x 32KB (A 16KB + B 16KB per buffer), 1 block/CU
//   - counted vmcnt: stage tile t+1 BEFORE waiting vmcnt(4) for tile t; the
//     prefetch stays in flight across the whole ~1100cy compute phase.
//     NEVER vmcnt(0) in the main loop.
// NOTE: LDS dest pointer must be a real addrspace(3) cast of the shared-mem
// pointer (compiler addrspacecast). (uint32_t)(uintptr_t) truncation = garbage.

typedef __bf16 bf16x8 __attribute__((ext_vector_type(8)));
typedef float f32x4 __attribute__((ext_vector_type(4)));

__device__ __forceinline__ void async_copy16(const void* g, void* l) {
  __builtin_amdgcn_global_load_lds(
      (const __attribute__((address_space(1))) uint32_t*)g,
      (__attribute__((address_space(3))) uint32_t*)l,
      16, 0, 0);
}

__device__ __forceinline__ float sgn(float v) {
  return (v > 0.f) ? 1.f : ((v < 0.f) ? -1.f : 0.f);
}

__device__ __forceinline__ void store_out(float* p, float v) { *p = v; }
__device__ __forceinline__ void store_out(__hip_bfloat16* p, float v) { *p = __float2bfloat16(v); }

// fp32 -> bf16, 8 elements/thread, vectorized
__global__ __launch_bounds__(256) void convert_x(const float* __restrict__ x,
                                                 __hip_bfloat16* __restrict__ xb,
                                                 int n) {
  int i = (blockIdx.x * 256 + threadIdx.x) * 8;
  if (i >= n) return;
  const float4* p0 = (const float4*)(x + i);
  float4 a = p0[0], b = p0[1];
  __hip_bfloat16 o[8] = {
      __float2bfloat16(a.x), __float2bfloat16(a.y), __float2bfloat16(a.z), __float2bfloat16(a.w),
      __float2bfloat16(b.x), __float2bfloat16(b.y), __float2bfloat16(b.z), __float2bfloat16(b.w)};
  *(uint4*)(xb + i) = *(const uint4*)o;
}

// Wb1[s][k] = sign(V[s][k]) * v2[k] * v1[s] * u2[s]   (s<1024: branch1, else branch2)
__global__ __launch_bounds__(256) void prep_w1(
    const float* __restrict__ V, const float* __restrict__ v2,
    const float* __restrict__ v1, const float* __restrict__ u2,
    const float* __restrict__ V_R, const float* __restrict__ v2_R,
    const float* __restrict__ v1_R, const float* __restrict__ u2_R,
    __hip_bfloat16* __restrict__ W) {
  int g = blockIdx.x * 256 + threadIdx.x;  // one thread -> 8 consecutive k
  int k = (g & 511) * 8;                   // 4096 / 8 = 512 groups per row
  int s = g >> 9;                          // 0..2047
  const float *Vp, *v2p;
  float rs;
  if (s < 1024) {
    Vp = V + s * 4096 + k; v2p = v2 + k; rs = v1[s] * u2[s];
  } else {
    int ss = s - 1024;
    Vp = V_R + ss * 4096 + k; v2p = v2_R + k; rs = v1_R[ss] * u2_R[ss];
  }
  __hip_bfloat16 o[8];
#pragma unroll
  for (int e = 0; e < 8; ++e)
    o[e] = __float2bfloat16(sgn(Vp[e]) * v2p[e] * rs);
  *(uint4*)(W + s * 4096 + k) = *(const uint4*)o;
}

// Wb2[j][s] = sign(U[j][s]) * u1[j]  (s<1024 branch1, else branch2)
__global__ __launch_bounds__(256) void prep_w2(
    const float* __restrict__ U, const float* __restrict__ u1,
    const float* __restrict__ U_R, const float* __restrict__ u1_R,
    __hip_bfloat16* __restrict__ W) {
  int g = blockIdx.x * 256 + threadIdx.x;  // one thread -> 8 consecutive s
  int s = (g & 255) * 8;                   // 2048 / 8 = 256 groups per row
  int j = g >> 8;                          // 0..4095
  const float* Up;
  float sc;
  if (s < 1024) { Up = U + j * 1024 + s;            sc = u1[j]; }
  else          { Up = U_R + j * 1024 + (s - 1024); sc = u1_R[j]; }
  __hip_bfloat16 o[8];
#pragma unroll
  for (int e = 0; e < 8; ++e)
    o[e] = __float2bfloat16(sgn(Up[e]) * sc);
  *(uint4*)(W + j * 2048 + s) = *(const uint4*)o;
}

// C[M][N] = A[M][K] @ Bt[N][K]^T (+bias), bf16 in, fp32 acc.
// 256x256 block tile, 8 waves (2Mx4N), each wave 128x64 = 8x4 MFMA 16x16x32 tiles.
// BK=32, double-buffered LDS (2 x 32KB). Per buffer: A [0,16K) 1024 slots of 16B
// (slot = chunk*256 + row, chunk = k-octet), B [16K,32K) same with col-rows.
// global_load_lds dest = wave base + lane*16 (wave-uniform-base constraint):
// thread t stages slots {t, t+512} of A and of B (4 copies per tile).
//
// K-loop (counted vmcnt, 2 barriers/step, prefetch-before-wait):
//   prologue: stage(0 -> buf0)
//   iter t:   [bar_A: all waves done READING buf(t+1)=buf(t-1) from iter t-1]
//             stage(t+1 -> buf^1)   <- in flight across all of compute(t)
//             s_waitcnt vmcnt(4)    <- tile t's 4 copies landed (t+1's fly)
//             [bar_B: every wave's tile-t copies landed]
//             compute(buf)          <- 12 ds_read_b128 + 32 MFMA per wave
template <typename OutT>
__global__ __launch_bounds__(512, 2) void gemm_bt(
    const __hip_bfloat16* __restrict__ A,
    const __hip_bfloat16* __restrict__ Bt,
    OutT* __restrict__ C,
    const float* __restrict__ bias,
    int K, int N) {
  __shared__ char smem[65536];  // 2 buffers x (A 16KB + B 16KB)
  const int t = threadIdx.x;
  const int lane = t & 63;
  const int w = t >> 6;
  const int wm = (w >> 2) << 7;   // 0 / 128
  const int wn = (w & 3) << 6;    // 0 / 64 / 128 / 192

  // L2-aware block swizzle: column-group-major (G=2 block-cols per group),
  // then contiguous chunk per XCD (nwg % 8 == 0 for our grids).
  // Per-XCD B footprint = 2 panels (4MB gemm1 / 2MB gemm2) ~ L2-resident.
  const int gx = gridDim.x;
  const int gy = gridDim.y;
  const int nwg = gx * gy;
  int lin = blockIdx.y * gx + blockIdx.x;
  {
    const int xcd = lin & 7, idx = lin >> 3, q = nwg >> 3;
    lin = xcd * q + idx;
  }
  const int grpsz = gy << 1;          // gy rows * 2 cols per group
  const int cg = lin / grpsz;
  const int rem = lin - cg * grpsz;
  const int bm = (rem >> 1) << 8;                  // row block * 256
  const int bn = ((cg << 1) + (rem & 1)) << 8;     // col block * 256

  const int quad = lane >> 4;
  const int l16 = lane & 15;

  f32x4 acc[8][4] = {};

  // staging: per buffer 1024 A-slots + 1024 B-slots; 512 threads -> thread t
  // owns A slots {t, t+512} and B slots {t, t+512}. slot = chunk*256 + row.
  const int srow = t & 255, sch = t >> 8;  // chunk 0/1 (slots t), +2 for t+512
  const __hip_bfloat16* gA0 = A + (bm + srow) * K + sch * 8;
  const __hip_bfloat16* gB0 = Bt + (bn + srow) * K + sch * 8;
  const int oA0 = t * 16,          oA1 = (t + 512) * 16;
  const int oB0 = 16384 + t * 16,  oB1 = 16384 + (t + 512) * 16;

  auto stage = [&](int k0, int bufOff) {
    char* base = smem + bufOff;
    async_copy16(gA0 + k0, base + oA0);
    async_copy16(gA0 + k0 + 16, base + oA1);   // chunks 2,3 (k +16 elems)
    async_copy16(gB0 + k0, base + oB0);
    async_copy16(gB0 + k0 + 16, base + oB1);
  };
  auto compute = [&](int bufOff) {
    const char* base = smem + bufOff;
    bf16x8 a[8], b[4];
#pragma unroll
    for (int i = 0; i < 8; ++i)
      a[i] = *(const bf16x8*)(base + ((quad << 8) + wm + (i << 4) + l16) * 16);
#pragma unroll
    for (int j = 0; j < 4; ++j)
      b[j] = *(const bf16x8*)(base + 16384 + ((quad << 8) + wn + (j << 4) + l16) * 16);
#pragma unroll
    for (int i = 0; i < 8; ++i)
#pragma unroll
      for (int j = 0; j < 4; ++j)
        acc[i][j] = __builtin_amdgcn_mfma_f32_16x16x32_bf16(a[i], b[j], acc[i][j], 0, 0, 0);
  };

  const int NT = K >> 5;  // K/32 tiles
  stage(0, 0);
  int cur = 0;
  for (int tt = 0; tt < NT; ++tt) {
    if (tt > 0) {
      __builtin_amdgcn_s_barrier();          // bar_A: buf^1's readers are done
      asm volatile("" ::: "memory");
    }
    if (tt + 1 < NT) {
      stage((tt + 1) << 5, cur ^ 32768);     // prefetch next tile
      asm volatile("s_waitcnt vmcnt(4)" ::: "memory");  // tile t landed
    } else {
      asm volatile("s_waitcnt vmcnt(0)" ::: "memory");  // last tile: drain
    }
    __builtin_amdgcn_s_barrier();            // bar_B: all waves' tile-t landed
    asm volatile("" ::: "memory");
    compute(cur);
    cur ^= 32768;
  }

  // epilogue: C/D layout col=lane&15, row=quad*4+reg
#pragma unroll
  for (int j = 0; j < 4; ++j) {
    int col = bn + wn + (j << 4) + l16;
    float bv = bias ? bias[col] : 0.0f;
#pragma unroll
    for (int i = 0; i < 8; ++i) {
      int row0 = bm + wm + (i << 4) + (quad << 2);
#pragma unroll
      for (int r = 0; r < 4; ++r)
        store_out(&C[(row0 + r) * N + col], acc[i][j][r] + bv);
    }
  }
}

extern "C" void kernel_launch(void* const* d_in, const int* in_sizes, int n_in,
                              void* d_out, int out_size, void* d_ws, size_t ws_size,
                              hipStream_t stream) {
  const float* x    = (const float*)d_in[0];
  const float* V    = (const float*)d_in[1];
  const float* U    = (const float*)d_in[2];
  const float* v2   = (const float*)d_in[3];
  const float* v1   = (const float*)d_in[4];
  const float* u2   = (const float*)d_in[5];
  const float* u1   = (const float*)d_in[6];
  const float* V_R  = (const float*)d_in[7];
  const float* U_R  = (const float*)d_in[8];
  const float* v2_R = (const float*)d_in[9];
  const float* v1_R = (const float*)d_in[10];
  const float* u2_R = (const float*)d_in[11];
  const float* u1_R = (const float*)d_in[12];
  const float* bias = (const float*)d_in[13];

  __hip_bfloat16* Xb  = (__hip_bfloat16*)d_ws;          // 8192*4096
  __hip_bfloat16* Wb1 = Xb + 8192 * 4096;               // 2048*4096
  __hip_bfloat16* Wb2 = Wb1 + 2048 * 4096;              // 4096*2048
  __hip_bfloat16* H   = Wb2 + 4096 * 2048;              // 8192*2048
  float* Y = (float*)d_out;

  const int nx = 8192 * 4096;
  convert_x<<<nx / (256 * 8), 256, 0, stream>>>(x, Xb, nx);
  prep_w1<<<4096, 256, 0, stream>>>(V, v2, v1, u2, V_R, v2_R, v1_R, u2_R, Wb1);
  prep_w2<<<4096, 256, 0, stream>>>(U, u1, U_R, u1_R, Wb2);

  // H[8192][2048] = Xb @ Wb1^T   (grid 8x32 = 256 blocks = 1/CU)
  gemm_bt<__hip_bfloat16><<<dim3(2048 / 256, 8192 / 256), 512, 0, stream>>>(
      Xb, Wb1, H, nullptr, 4096, 2048);
  // Y[8192][4096] = H @ Wb2^T + bias   (grid 16x32 = 512 blocks)
  gemm_bt<float><<<dim3(4096 / 256, 8192 / 256), 512, 0, stream>>>(
      H, Wb2, Y, bias, 2048, 4096);
}